// Round 8
// baseline (350.581 us; speedup 1.0000x reference)
//
#include <hip/hip_runtime.h>
#include <hip/hip_bf16.h>

using bf16 = __hip_bfloat16;
typedef __bf16 bf16x8v __attribute__((ext_vector_type(8)));
typedef float f32x4 __attribute__((ext_vector_type(4)));

static constexpr int SEQ = 2048;
static constexpr int DMODEL = 2048;
static constexpr int NHEADS = 16;
static constexpr int DQKC = 192;   // nope 128 + rope 64
static constexpr int DVC = 128;
static constexpr int DQC = 1536;
static constexpr int DCC = 512;
static constexpr int HQK = NHEADS * DQKC;  // 3072
static constexpr int HV = NHEADS * DVC;    // 2048
static constexpr int NKV = HQK + HV;       // 5120
static constexpr int NDOWN = DQC + DCC;    // 2048

typedef __attribute__((address_space(1))) const void* gas_ptr;
typedef __attribute__((address_space(3))) void* las_ptr;

__device__ __forceinline__ void g2l16(const void* g, void* l) {
  __builtin_amdgcn_global_load_lds((gas_ptr)g, (las_ptr)l, 16, 0, 0);
}

// ---------------- templated GEMM core: C[M,N] = alpha * A@Bt^T ----------------
// m97-verified structure: 128x128 tile, BK=32, 4 waves as 2x2 of 64x64,
// 16 MFMA + 8 ds_read_b128 per wave-iter. (64x128 measured 253 TF / 17.6%
// MfmaUtil in round 7 — too little MFMA per barrier; 128x128 is the keeper.)
template <int BM, int BN>
__device__ __forceinline__ void gemm_core(
    const bf16* __restrict__ A, int lda,
    const bf16* __restrict__ Bt, int ldb,
    void* __restrict__ Cv, int ldc,
    int K, float alpha, int c_fp32, long tm, long tn, char* smem)
{
  constexpr int FM = BM / 32, FN = BN / 32;
  bf16* As = (bf16*)smem;              // [BM][32]
  char* Bsm = smem + BM * 64;          // [BN][32]
  bf16* Bs = (bf16*)Bsm;
  const int tid = threadIdx.x;
  const int w = tid >> 6, lane = tid & 63;
  const int wm = (w >> 1) * (BM / 2), wn = (w & 1) * (BN / 2);
  const int m0 = lane & 15, q8 = (lane >> 4) * 8;
  f32x4 acc[FM][FN] = {};
  for (int bk = 0; bk < K; bk += 32) {
#pragma unroll
    for (int i = 0; i < BM / 64; i++) {
      const int u = i * 256 + tid;
      g2l16(A + (tm + (u >> 2)) * (long)lda + bk + (u & 3) * 8, smem + u * 16);
    }
#pragma unroll
    for (int i = 0; i < BN / 64; i++) {
      const int u = i * 256 + tid;
      g2l16(Bt + (tn + (u >> 2)) * (long)ldb + bk + (u & 3) * 8, Bsm + u * 16);
    }
    __syncthreads();
    bf16x8v af[FM], bfv[FN];
#pragma unroll
    for (int i = 0; i < FM; i++)
      af[i] = *reinterpret_cast<const bf16x8v*>(&As[(wm + i * 16 + m0) * 32 + q8]);
#pragma unroll
    for (int i = 0; i < FN; i++)
      bfv[i] = *reinterpret_cast<const bf16x8v*>(&Bs[(wn + i * 16 + m0) * 32 + q8]);
#pragma unroll
    for (int mi = 0; mi < FM; mi++)
#pragma unroll
      for (int ni = 0; ni < FN; ni++)
        acc[mi][ni] = __builtin_amdgcn_mfma_f32_16x16x32_bf16(af[mi], bfv[ni], acc[mi][ni], 0, 0, 0);
    __syncthreads();
  }
  const int q4 = (lane >> 4) * 4;
  float* Cf = (float*)Cv;
  bf16* Cb = (bf16*)Cv;
#pragma unroll
  for (int mi = 0; mi < FM; mi++) {
#pragma unroll
    for (int r = 0; r < 4; r++) {
      const long row = tm + wm + mi * 16 + q4 + r;
#pragma unroll
      for (int ni = 0; ni < FN; ni++) {
        const long idx = row * ldc + tn + wn + ni * 16 + m0;
        const float v = acc[mi][ni][r] * alpha;
        if (c_fp32) Cf[idx] = v;
        else Cb[idx] = __float2bfloat16(v);
      }
    }
  }
}

__global__ __launch_bounds__(256) void gemm128(
    const bf16* __restrict__ A, int lda, const bf16* __restrict__ Bt, int ldb,
    void* __restrict__ Cv, int ldc, int K, float alpha, int c_fp32)
{
  __shared__ __align__(16) char smem[(128 + 128) * 64];
  gemm_core<128, 128>(A, lda, Bt, ldb, Cv, ldc, K, alpha, c_fp32,
                      (long)blockIdx.y * 128, (long)blockIdx.x * 128, smem);
}

// two independent GEMMs in one launch (grid.x split at nx1)
__global__ __launch_bounds__(256) void gemm_dual(
    const bf16* __restrict__ A1, int lda1, const bf16* __restrict__ B1, int ldb1,
    void* __restrict__ C1, int ldc1, int K1, float alpha1, int nx1,
    const bf16* __restrict__ A2, int lda2, const bf16* __restrict__ B2, int ldb2,
    void* __restrict__ C2, int ldc2, int K2)
{
  __shared__ __align__(16) char smem[(128 + 128) * 64];
  if ((int)blockIdx.x < nx1)
    gemm_core<128, 128>(A1, lda1, B1, ldb1, C1, ldc1, K1, alpha1, 0,
                        (long)blockIdx.y * 128, (long)blockIdx.x * 128, smem);
  else
    gemm_core<128, 128>(A2, lda2, B2, ldb2, C2, ldc2, K2, 1.f, 0,
                        (long)blockIdx.y * 128, (long)((int)blockIdx.x - nx1) * 128, smem);
}

// ---------------- fused flash attention v3.1 (96-key tiles, 68KB LDS) --------
// 512 blocks x 256 thr; block = (64-row q-tile, head), pairing swizzle.
// Ks: 96 keys x 24 fg : unit = key*24 + (fg ^ (key&7))          [36864 B]
// Vs: 128 dv x 16 kg  : unit = dv*16 + (kg ^ (dv&15))           [32768 B] at +36864
//     NOTE: all 16 kg staged UNGUARDED — a divergent guard on g2l16 shifts the
//     wave-uniform LDS base (readfirstlane of first ACTIVE lane) and corrupts
//     the write (round-5 bug). Logical kg 12..15 are written but never read.
// Ps: 64 rows x 16 k8 : unit = row*16 + (k8 ^ (row&15))         [16384 B] aliases Ks
__global__ __launch_bounds__(256) void flash_attn(
    const bf16* __restrict__ qf,   // [SEQ][HQK], 1/sqrt(dqk) pre-folded
    const bf16* __restrict__ kvf,  // [SEQ][NKV], k at col h*192
    const bf16* __restrict__ vT,   // [HV][SEQ]
    bf16* __restrict__ attn)       // [SEQ][HV]
{
  __shared__ __align__(16) char smem[69632];
  const int fid = blockIdx.x;
  const int half = fid >> 8;
  const int r8 = fid & 255;
  const int h = r8 & 15;
  const int t8 = r8 >> 4;
  const int tile = half ? (31 - t8) : t8;
  const int nkt = (tile * 64 + 63) / 96 + 1;  // 96-key tiles to cover diagonal
  const int tid = threadIdx.x;
  const int w = tid >> 6, lane = tid & 63;
  const int m0 = lane & 15, quad = lane >> 4;
  const int prow = w * 16 + m0;
  const long qrow = (long)tile * 64 + prow;

  bf16x8v qfr[6];
#pragma unroll
  for (int s = 0; s < 6; s++)
    qfr[s] = *reinterpret_cast<const bf16x8v*>(
        &qf[qrow * HQK + h * DQKC + s * 32 + quad * 8]);

  f32x4 O[8] = {};
  float mrow = -1e30f, lrow = 0.f;

  for (int kt = 0; kt < nkt; ++kt) {
    const int key0 = kt * 96;
    // stage K: 2304 units (9 rounds)
#pragma unroll
    for (int i = 0; i < 9; i++) {
      const int u = i * 256 + tid;
      const int key = u / 24;
      const int fg = (u - key * 24) ^ (key & 7);
      g2l16(kvf + (long)(key0 + key) * NKV + h * DQKC + fg * 8, smem + u * 16);
    }
    // stage V: all 2048 units, no guard (see header comment)
#pragma unroll
    for (int i = 0; i < 8; i++) {
      const int u = i * 256 + tid;
      const int dv = u >> 4;
      const int kg = (u & 15) ^ (dv & 15);
      g2l16(vT + (long)(h * DVC + dv) * SEQ + key0 + kg * 8, smem + 36864 + u * 16);
    }
    __syncthreads();

    // S^T = K @ Q^T : C row = key (quad*4+r), col = qrow (m0)
    f32x4 S[6] = {};
#pragma unroll
    for (int s = 0; s < 6; s++) {
#pragma unroll
      for (int mi = 0; mi < 6; mi++) {
        const int kl = mi * 16 + m0;
        const int idx = kl * 24 + ((s * 4 + quad) ^ (m0 & 7));
        const bf16x8v kb = *reinterpret_cast<const bf16x8v*>(smem + idx * 16);
        S[mi] = __builtin_amdgcn_mfma_f32_16x16x32_bf16(kb, qfr[s], S[mi], 0, 0, 0);
      }
    }
    if (key0 + 95 > tile * 64) {  // tile touches/passes the diagonal
#pragma unroll
      for (int mi = 0; mi < 6; mi++)
#pragma unroll
        for (int r = 0; r < 4; r++)
          if (key0 + mi * 16 + quad * 4 + r > qrow) S[mi][r] = -1e30f;
    }

    // wave-local online softmax (row = m0; partners at lane^16, lane^32)
    float fm = -1e30f;
#pragma unroll
    for (int mi = 0; mi < 6; mi++)
#pragma unroll
      for (int r = 0; r < 4; r++) fm = fmaxf(fm, S[mi][r]);
    fm = fmaxf(fm, __shfl_xor(fm, 16, 64));
    fm = fmaxf(fm, __shfl_xor(fm, 32, 64));
    const float newm = fmaxf(mrow, fm);
    const float alph = __expf(mrow - newm);
    mrow = newm;
    float ps = 0.f;
#pragma unroll
    for (int mi = 0; mi < 6; mi++)
#pragma unroll
      for (int r = 0; r < 4; r++) {
        const float p = __expf(S[mi][r] - newm);
        S[mi][r] = p;
        ps += p;
      }
    ps += __shfl_xor(ps, 16, 64);
    ps += __shfl_xor(ps, 32, 64);
    lrow = lrow * alph + ps;

    __syncthreads();  // all QK reads of Ks done before Ps (alias) is written

    // P -> LDS (b64, wave-private rows)
#pragma unroll
    for (int mi = 0; mi < 6; mi++) {
      const int k8 = mi * 2 + (quad >> 1);
      const int idx = prow * 16 + (k8 ^ (m0 & 15));
      unsigned short b[4];
#pragma unroll
      for (int r = 0; r < 4; r++) {
        const bf16 t = __float2bfloat16(S[mi][r]);
        b[r] = *reinterpret_cast<const unsigned short*>(&t);
      }
      *reinterpret_cast<uint2*>(smem + idx * 16 + (quad & 1) * 8) =
          make_uint2((unsigned)b[0] | ((unsigned)b[1] << 16),
                     (unsigned)b[2] | ((unsigned)b[3] << 16));
    }
    float aO[4];
#pragma unroll
    for (int r = 0; r < 4; r++) aO[r] = __shfl(alph, quad * 4 + r, 16);
#pragma unroll
    for (int ni = 0; ni < 8; ni++)
#pragma unroll
      for (int r = 0; r < 4; r++) O[ni][r] *= aO[r];
    // no barrier: PV reads only this wave's own Ps rows + Vs (staged pre-sync)

    // O += P @ V
#pragma unroll
    for (int ks = 0; ks < 3; ks++) {
      const int idxp = prow * 16 + ((ks * 4 + quad) ^ (m0 & 15));
      const bf16x8v pa = *reinterpret_cast<const bf16x8v*>(smem + idxp * 16);
#pragma unroll
      for (int ni = 0; ni < 8; ni++) {
        const int dv = ni * 16 + m0;
        const int idxv = dv * 16 + ((ks * 4 + quad) ^ (dv & 15));
        const bf16x8v vb = *reinterpret_cast<const bf16x8v*>(smem + 36864 + idxv * 16);
        O[ni] = __builtin_amdgcn_mfma_f32_16x16x32_bf16(pa, vb, O[ni], 0, 0, 0);
      }
    }
    __syncthreads();  // PV reads done before next iter's staging
  }

  float lO[4];
#pragma unroll
  for (int r = 0; r < 4; r++) lO[r] = 1.f / __shfl(lrow, quad * 4 + r, 16);
#pragma unroll
  for (int ni = 0; ni < 8; ni++)
#pragma unroll
    for (int r = 0; r < 4; r++)
      attn[((long)tile * 64 + w * 16 + quad * 4 + r) * HV + h * DVC + ni * 16 + m0] =
          __float2bfloat16(O[ni][r] * lO[r]);
}

// ---------------- small kernels ----------------
__device__ __forceinline__ float tofl(float x) { return x; }
__device__ __forceinline__ float tofl(bf16 x) { return __bfloat162float(x); }

template <typename TIN>
__global__ __launch_bounds__(256) void transpose_cast(const TIN* __restrict__ in,
                                                      bf16* __restrict__ out,
                                                      int inStride, int outStride) {
  __shared__ float t[32][33];
  const int bx = blockIdx.x * 32, by = blockIdx.y * 32;
  const int tx = threadIdx.x, ty = threadIdx.y;
#pragma unroll
  for (int j = 0; j < 32; j += 8)
    t[ty + j][tx] = tofl(in[(long)(by + ty + j) * inStride + bx + tx]);
  __syncthreads();
#pragma unroll
  for (int j = 0; j < 32; j += 8)
    out[(long)(bx + ty + j) * outStride + by + tx] = __float2bfloat16(t[tx][ty + j]);
}

struct TPar { const float* src; bf16* dst; int C; int R; int gw; int nblk; };

// six independent fp32->bf16 transposes in one launch
__global__ __launch_bounds__(256) void transpose6(TPar a, TPar b, TPar c,
                                                  TPar d, TPar e, TPar f) {
  int blk = blockIdx.x;
  TPar p;
  if (blk < a.nblk) p = a;
  else { blk -= a.nblk;
  if (blk < b.nblk) p = b;
  else { blk -= b.nblk;
  if (blk < c.nblk) p = c;
  else { blk -= c.nblk;
  if (blk < d.nblk) p = d;
  else { blk -= d.nblk;
  if (blk < e.nblk) p = e;
  else { blk -= e.nblk; p = f; } } } } }
  const int bx = (blk % p.gw) * 32, by = (blk / p.gw) * 32;
  __shared__ float t[32][33];
  const int tx = threadIdx.x, ty = threadIdx.y;
#pragma unroll
  for (int j = 0; j < 32; j += 8)
    t[ty + j][tx] = p.src[(long)(by + ty + j) * p.C + bx + tx];
  __syncthreads();
#pragma unroll
  for (int j = 0; j < 32; j += 8)
    p.dst[(long)(bx + ty + j) * p.R + by + tx] = __float2bfloat16(t[tx][ty + j]);
}

__global__ __launch_bounds__(256) void cast_f32_bf16(const float* __restrict__ in,
                                                     bf16* __restrict__ out, int n4) {
  int i = blockIdx.x * 256 + threadIdx.x;
  if (i < n4) {
    const float4 v = ((const float4*)in)[i];
    out[i * 4 + 0] = __float2bfloat16(v.x);
    out[i * 4 + 1] = __float2bfloat16(v.y);
    out[i * 4 + 2] = __float2bfloat16(v.z);
    out[i * 4 + 3] = __float2bfloat16(v.w);
  }
}

__global__ __launch_bounds__(256) void rope_qk(bf16* __restrict__ q, bf16* __restrict__ k) {
  const int idx = blockIdx.x * 256 + threadIdx.x;  // SEQ*NHEADS*32 threads
  const int i = idx & 31;
  const int h = (idx >> 5) & 15;
  const int l = idx >> 9;
  const float inv = powf(10000.f, -(float)i * (1.f / 32.f));
  float s, c;
  sincosf((float)l * inv, &s, &c);
  const long qb = (long)l * HQK + h * DQKC + 128;
  const long kb = (long)l * NKV + h * DQKC + 128;
  {
    float x0 = __bfloat162float(q[qb + i]);
    float x1 = __bfloat162float(q[qb + i + 32]);
    q[qb + i] = __float2bfloat16(x0 * c - x1 * s);
    q[qb + i + 32] = __float2bfloat16(x1 * c + x0 * s);
  }
  {
    float x0 = __bfloat162float(k[kb + i]);
    float x1 = __bfloat162float(k[kb + i + 32]);
    k[kb + i] = __float2bfloat16(x0 * c - x1 * s);
    k[kb + i + 32] = __float2bfloat16(x1 * c + x0 * s);
  }
}

extern "C" void kernel_launch(void* const* d_in, const int* in_sizes, int n_in,
                              void* d_out, int out_size, void* d_ws, size_t ws_size,
                              hipStream_t stream) {
  const float* hs      = (const float*)d_in[0];
  // d_in[1] attention_mask: exact causal mask; applied analytically.
  const float* Wq_down = (const float*)d_in[2];
  const float* Wq_up   = (const float*)d_in[3];
  const float* Wkv_down= (const float*)d_in[4];
  const float* Wk_up   = (const float*)d_in[5];
  const float* Wv_up   = (const float*)d_in[6];
  const float* Wo      = (const float*)d_in[7];

  char* p = (char*)d_ws;
  auto alloc = [&](long elems) {
    bf16* r = (bf16*)p;
    p += ((elems * 2 + 255) / 256) * 256;
    return r;
  };
  bf16* hsb   = alloc((long)SEQ * DMODEL);
  bf16* W1T   = alloc((long)NDOWN * DMODEL);
  bf16* WquT  = alloc((long)HQK * DQC);
  bf16* WkvuT = alloc((long)NKV * DCC);
  bf16* WoT   = alloc((long)DMODEL * HV);
  bf16* qdc   = alloc((long)SEQ * NDOWN);
  bf16* qf    = alloc((long)SEQ * HQK);
  bf16* kvf   = alloc((long)SEQ * NKV);
  bf16* vT    = alloc((long)HV * SEQ);
  bf16* attn  = alloc((long)SEQ * HV);

  const float scale = 0.07216878364870323f;  // 1/sqrt(192), folded into q

  const dim3 b256(256);
  const dim3 tb(32, 8);
  cast_f32_bf16<<<dim3(SEQ * DMODEL / 4 / 256), b256, 0, stream>>>(hs, hsb, SEQ * DMODEL / 4);

  TPar ta{Wq_down,  W1T,                      DQC,    DMODEL, DQC / 32,    (DQC / 32) * (DMODEL / 32)};
  TPar tb2{Wkv_down, W1T + (long)DQC * DMODEL, DCC,    DMODEL, DCC / 32,    (DCC / 32) * (DMODEL / 32)};
  TPar tc{Wq_up,    WquT,                     HQK,    DQC,    HQK / 32,    (HQK / 32) * (DQC / 32)};
  TPar td{Wk_up,    WkvuT,                    HQK,    DCC,    HQK / 32,    (HQK / 32) * (DCC / 32)};
  TPar te{Wv_up,    WkvuT + (long)HQK * DCC,  HV,     DCC,    HV / 32,     (HV / 32) * (DCC / 32)};
  TPar tf{Wo,       WoT,                      DMODEL, HV,     DMODEL / 32, (DMODEL / 32) * (HV / 32)};
  const int tblk = ta.nblk + tb2.nblk + tc.nblk + td.nblk + te.nblk + tf.nblk;
  transpose6<<<dim3(tblk), tb, 0, stream>>>(ta, tb2, tc, td, te, tf);

  // fused down-projection: [qd | ckv] = hsb @ [Wq_down | Wkv_down]
  gemm128<<<dim3(NDOWN / 128, SEQ / 128), b256, 0, stream>>>(
      hsb, DMODEL, W1T, DMODEL, qdc, NDOWN, DMODEL, 1.f, 0);

  // q up (scale folded) + fused k/v up, one launch (1024 blocks)
  gemm_dual<<<dim3(HQK / 128 + NKV / 128, SEQ / 128), b256, 0, stream>>>(
      qdc, NDOWN, WquT, DQC, qf, HQK, DQC, scale, HQK / 128,
      qdc + DQC, NDOWN, WkvuT, DCC, kvf, NKV, DCC);

  rope_qk<<<dim3(SEQ * NHEADS * 32 / 256), b256, 0, stream>>>(qf, kvf);
  transpose_cast<bf16><<<dim3(HV / 32, SEQ / 32), tb, 0, stream>>>(kvf + HQK, vT, NKV, SEQ);

  // fused attention
  flash_attn<<<dim3(512), b256, 0, stream>>>(qf, kvf, vT, attn);

  // output projection (fp32 out)
  gemm128<<<dim3(DMODEL / 128, SEQ / 128), b256, 0, stream>>>(
      attn, HV, WoT, HV, d_out, DMODEL, HV, 1.f, 1);
}